// Round 3
// baseline (336.202 us; speedup 1.0000x reference)
//
#include <hip/hip_runtime.h>

#define PP 8732
#define NB 20
#define NC 21
#define BTH 256
#define NW (BTH/64)
#define SA 8
#define CHA ((PP + SA - 1)/SA)   // 1092 priors per match block
#define SC 32
#define CHC ((PP + SC - 1)/SC)   // 273 priors per rank block

// ws layout (bytes):
//   0     : keys  u64 [B][NB]   per-truth best-prior packed keys
//   20480 : facc  float[8]      0=loss_l 1=posce 2=special_ce 3=negsum_total
//   20512 : iacc  int[8]        0=special_flag (flat index 0 was negative)
//   20544 : npos  int[B]
//   32768 : rank  float[B][PP]  pass A: best_truth_overlap; pass C: loss_c rank value
//   32768+B*PP*4 : idx uchar[B][PP]
#define OFF_FACC 20480
#define OFF_IACC 20512
#define OFF_NPOS 20544
#define OFF_RANK 32768

__device__ __forceinline__ float sl1(float d){
  float a = fabsf(d);
  return a < 1.0f ? 0.5f*a*a : a - 0.5f;
}

// ---- A: IoU matching. grid (B, SA) ----
extern "C" __global__ void __launch_bounds__(BTH)
mb_match(const float* __restrict__ priors, const float* __restrict__ targets,
         float* __restrict__ rank, unsigned char* __restrict__ idxa,
         unsigned long long* __restrict__ keys)
{
  const int b = blockIdx.x, tid = threadIdx.x, lane = tid & 63;
  __shared__ float s_tr[NB][4];
  if (tid < NB*5){
    int n = tid/5, k2 = tid - n*5;
    float v = targets[((long)b*NB + n)*5 + k2];
    if (k2 < 4) s_tr[n][k2] = v;
  }
  __syncthreads();

  unsigned long long bk[NB];
  #pragma unroll
  for (int n=0;n<NB;n++) bk[n]=0ULL;

  const int base = blockIdx.y*CHA;
  const int end  = (base + CHA < PP) ? base + CHA : PP;
  for (int p = base + tid; p < end; p += BTH){
    float4 pr = reinterpret_cast<const float4*>(priors)[p];
    float bx1 = pr.x - pr.z*0.5f, by1 = pr.y - pr.w*0.5f;
    float bx2 = pr.x + pr.z*0.5f, by2 = pr.y + pr.w*0.5f;
    float area_b = (bx2-bx1)*(by2-by1);
    float bestov = -1.0f; int bestn = 0;
    #pragma unroll
    for (int n=0;n<NB;n++){
      float tx1=s_tr[n][0], ty1=s_tr[n][1], tx2=s_tr[n][2], ty2=s_tr[n][3];
      float lx=fmaxf(tx1,bx1), ly=fmaxf(ty1,by1);
      float rx=fminf(tx2,bx2), ry=fminf(ty2,by2);
      float w=fmaxf(rx-lx,0.f), h=fmaxf(ry-ly,0.f);
      float inter=w*h;
      float area_a=(tx2-tx1)*(ty2-ty1);
      float iou = inter/(area_a+area_b-inter);
      if (iou > bestov){ bestov=iou; bestn=n; }          // strict > = first-max over n
      unsigned long long key = ((unsigned long long)__float_as_uint(iou)<<32)
                             | (unsigned long long)(0xFFFFFFFFu - (unsigned)p);
      if (key > bk[n]) bk[n] = key;                      // max iou, tie -> min p
    }
    rank[(long)b*PP + p] = bestov;
    idxa[(long)b*PP + p] = (unsigned char)bestn;
  }

  #pragma unroll
  for (int n=0;n<NB;n++){
    unsigned long long k2 = bk[n];
    #pragma unroll
    for (int o=32;o;o>>=1){ unsigned long long w=__shfl_down(k2,o,64); if (w>k2) k2=w; }
    if (lane==0 && k2) atomicMax(&keys[b*NB+n], k2);
  }
}

// ---- B: scatter overrides, ascending n. 1 block, one thread per row ----
extern "C" __global__ void mb_scatter(float* __restrict__ rank,
                                      unsigned char* __restrict__ idxa,
                                      const unsigned long long* __restrict__ keys,
                                      int B)
{
  int b = threadIdx.x;
  if (b >= B) return;
  #pragma unroll
  for (int n=0;n<NB;n++){
    unsigned long long kk = keys[b*NB+n];
    int p = (int)(0xFFFFFFFFu - (unsigned)(kk & 0xFFFFFFFFULL));
    rank[(long)b*PP + p] = 2.0f;
    idxa[(long)b*PP + p] = (unsigned char)n;   // ascending overwrite => max n wins
  }
}

// ---- C: conf_t, logsumexp, positive losses, rank values. grid (B, SC) ----
// Stages the block's contiguous conf chunk (273 priors x 21 cls = 22.9 KB) in LDS
// via coalesced dword loads; per-prior reads then hit LDS with a conflict-free
// 2-lanes/bank pattern (gcd(21,32)=1).
extern "C" __global__ void __launch_bounds__(BTH)
mb_rank(const float* __restrict__ loc_data, const float* __restrict__ conf_data,
        const float* __restrict__ priors, const float* __restrict__ targets,
        float* __restrict__ rank, const unsigned char* __restrict__ idxa,
        float* __restrict__ facc, int* __restrict__ iacc, int* __restrict__ nposa)
{
  const int b = blockIdx.x, tid = threadIdx.x, lane = tid & 63, wid = tid >> 6;
  const int base = blockIdx.y*CHC;
  const int cnt  = (base + CHC < PP) ? CHC : (PP - base);

  __shared__ float s_conf[CHC*NC];   // 22932 B
  __shared__ float s_tr[NB][4];
  __shared__ float s_lab[NB];
  __shared__ float s_red[2*NW];
  __shared__ int   s_redi[NW];

  if (tid < NB*5){
    int n = tid/5, k2 = tid - n*5;
    float v = targets[((long)b*NB + n)*5 + k2];
    if (k2 < 4) s_tr[n][k2] = v; else s_lab[n] = v;
  }
  // coalesced stage of conf chunk
  {
    const float* cbase = conf_data + ((long)b*PP + base)*NC;
    const int tot = cnt*NC;
    for (int i = tid; i < tot; i += BTH) s_conf[i] = cbase[i];
  }
  __syncthreads();

  float loss_l=0.f, posce=0.f; int np=0;
  for (int j = tid; j < cnt; j += BTH){
    const int p = base + j;
    const long gp = (long)b*PP + p;
    float ov = rank[gp];
    int idx = idxa[gp];
    int ct = (ov < 0.5f) ? 0 : ((int)s_lab[idx] + 1);
    const float* v = &s_conf[j*NC];
    float m=v[0];
    #pragma unroll
    for (int c=1;c<NC;c++) m=fmaxf(m,v[c]);
    float s=0.f;
    #pragma unroll
    for (int c=0;c<NC;c++) s += expf(v[c]-m);
    float lse = logf(s)+m;
    float rv;
    if (ct > 0){
      posce += lse - v[ct];
      np++;
      float tx1=s_tr[idx][0], ty1=s_tr[idx][1], tx2=s_tr[idx][2], ty2=s_tr[idx][3];
      float4 pr = reinterpret_cast<const float4*>(priors)[p];
      float g0 = ((tx1+tx2)*0.5f - pr.x) / (0.1f*pr.z);
      float g1 = ((ty1+ty2)*0.5f - pr.y) / (0.1f*pr.w);
      float g2 = logf((tx2-tx1)/pr.z) / 0.2f;
      float g3 = logf((ty2-ty1)/pr.w) / 0.2f;
      float4 ld = reinterpret_cast<const float4*>(loc_data)[gp];
      loss_l += sl1(ld.x-g0)+sl1(ld.y-g1)+sl1(ld.z-g2)+sl1(ld.w-g3);
      rv = 0.f;
    } else {
      if (b==0 && p==0){
        rv = lse - v[1];        // ranking value uses forced class 1
        facc[2] = lse - v[0];   // true ce if flat index 0 gets selected as negative
        iacc[0] = 1;
      } else {
        rv = lse - v[0];
      }
    }
    rank[gp] = rv;
  }

  #pragma unroll
  for (int o=32;o;o>>=1){
    loss_l += __shfl_down(loss_l,o,64);
    posce  += __shfl_down(posce,o,64);
    np     += __shfl_down(np,o,64);
  }
  if (lane==0){ s_red[wid]=loss_l; s_red[NW+wid]=posce; s_redi[wid]=np; }
  __syncthreads();
  if (tid==0){
    float a=0.f,c2=0.f; int ni=0;
    for (int w=0;w<NW;w++){ a+=s_red[w]; c2+=s_red[NW+w]; ni+=s_redi[w]; }
    if (a  != 0.f) atomicAdd(&facc[0], a);
    if (c2 != 0.f) atomicAdd(&facc[1], c2);
    if (ni) atomicAdd(&nposa[b], ni);
  }
}

// ---- D: per-row exact top-k via 3-level histogram radix select. grid (B) ----
extern "C" __global__ void __launch_bounds__(BTH)
mb_select(const float* __restrict__ rank, const int* __restrict__ nposa,
          float* __restrict__ facc, const int* __restrict__ iacc)
{
  const int b = blockIdx.x, tid = threadIdx.x, lane = tid & 63, wid = tid >> 6;
  __shared__ float s_val[PP];       // 34928 B
  __shared__ int   s_hist[2048];    // 8192 B
  __shared__ int   s_part[BTH];     // 1024 B
  __shared__ float s_scrf[NW];
  __shared__ int   s_scri[NW];
  __shared__ int   s_selb, s_G;

  // stage row into LDS, coalesced float4 (PP = 2183*4, row base 16B-aligned)
  const float4* rr = reinterpret_cast<const float4*>(rank + (long)b*PP);
  for (int i = tid; i < PP/4; i += BTH)
    reinterpret_cast<float4*>(s_val)[i] = rr[i];
  __syncthreads();

  const int num_pos = nposa[b];
  int k = num_pos*3; if (k > PP-1) k = PP-1;
  if (k <= 0) return;

  // 3-level radix select on float bits (all values >= 0 => uint-monotonic).
  // level 0: bits>>21 (11b); level 1: (bits>>10)&0x7FF (11b); level 2: bits&0x3FF (10b)
  int kk = k;
  unsigned sel = 0;   // accumulated selected high bits
  #pragma unroll
  for (int lvl=0; lvl<3; lvl++){
    const int sh   = (lvl==0) ? 21 : (lvl==1 ? 10 : 0);
    const unsigned msk = (lvl==2) ? 0x3FFu : 0x7FFu;
    for (int i=tid;i<2048;i+=BTH) s_hist[i]=0;
    __syncthreads();
    for (int p=tid;p<PP;p+=BTH){
      unsigned u = __float_as_uint(s_val[p]);
      bool ok = (lvl==0) ? true
              : (lvl==1) ? ((u>>21) == sel)
                         : ((u>>10) == sel);
      if (ok) atomicAdd(&s_hist[(u>>sh)&msk], 1);
    }
    __syncthreads();
    int ps=0;
    #pragma unroll
    for (int q=0;q<8;q++) ps += s_hist[tid*8+q];
    s_part[tid] = ps;
    __syncthreads();
    if (tid==0){
      int cum=0, g=BTH-1;
      for (; g>0; g--){ if (cum + s_part[g] >= kk) break; cum += s_part[g]; }
      int bkt = g*8+7;
      for (; bkt>0; bkt--){ int h = s_hist[bkt]; if (cum + h >= kk) break; cum += h; }
      s_selb = bkt; s_G = cum;  // cum = count strictly above bkt at this level
    }
    __syncthreads();
    int bkt = s_selb, G = s_G;
    kk -= G;
    sel = (lvl==0) ? (unsigned)bkt
        : (lvl==1) ? ((sel<<11)|(unsigned)bkt)
                   : ((sel<<10)|(unsigned)bkt);
    __syncthreads();
  }
  const unsigned vstar = sel;   // bit pattern of k-th largest; kk = tie count >= 1
  const int tie = kk;

  int cg=0; float sg=0.f;
  for (int p=tid;p<PP;p+=BTH){
    float rv = s_val[p];
    if (__float_as_uint(rv) > vstar){ cg++; sg += rv; }
  }
  #pragma unroll
  for (int o=32;o;o>>=1){ cg += __shfl_down(cg,o,64); sg += __shfl_down(sg,o,64); }
  __syncthreads();
  if (lane==0){ s_scri[wid]=cg; s_scrf[wid]=sg; }
  __syncthreads();
  if (tid==0){
    float sumG=0.f;
    for (int w=0;w<NW;w++) sumG+=s_scrf[w];
    float negsum = sumG + (float)tie * __uint_as_float(vstar);
    // flat-index-0 correction: ranked with class 1, true ce uses class 0.
    // index 0 is first among equal ties, so selected iff bits >= vstar.
    if (b==0 && iacc[0]){
      if (__float_as_uint(s_val[0]) >= vstar) negsum += facc[2] - s_val[0];
    }
    atomicAdd(&facc[3], negsum);
  }
}

// ---- E: final reduce, one wave ----
extern "C" __global__ void mb_out(const float* __restrict__ facc,
                                  const int* __restrict__ nposa,
                                  float* __restrict__ out, int B)
{
  int tid = threadIdx.x;
  int np = 0;
  for (int i = tid; i < B; i += 64) np += nposa[i];
  #pragma unroll
  for (int o=32;o;o>>=1) np += __shfl_down(np,o,64);
  if (tid==0){
    float Nf = (float)np;
    out[0] = facc[0] / Nf;
    out[1] = (facc[1] + facc[3]) / Nf;
  }
}

extern "C" void kernel_launch(void* const* d_in, const int* in_sizes, int n_in,
                              void* d_out, int out_size, void* d_ws, size_t ws_size,
                              hipStream_t stream) {
  const float* loc     = (const float*)d_in[0];
  const float* conf    = (const float*)d_in[1];
  const float* priors  = (const float*)d_in[2];
  const float* targets = (const float*)d_in[3];
  float* out = (float*)d_out;
  int B = in_sizes[0] / (PP*4);

  char* ws = (char*)d_ws;
  unsigned long long* keys = (unsigned long long*)ws;
  float* facc = (float*)(ws + OFF_FACC);
  int*   iacc = (int*)(ws + OFF_IACC);
  int*   nposa= (int*)(ws + OFF_NPOS);
  float* rank = (float*)(ws + OFF_RANK);
  unsigned char* idxa = (unsigned char*)(ws + OFF_RANK + (size_t)B*PP*4);

  hipMemsetAsync(d_ws, 0, OFF_RANK, stream);
  hipLaunchKernelGGL(mb_match,  dim3(B, SA), dim3(BTH), 0, stream, priors, targets, rank, idxa, keys);
  hipLaunchKernelGGL(mb_scatter, dim3(1), dim3(BTH), 0, stream, rank, idxa, keys, B);
  hipLaunchKernelGGL(mb_rank,   dim3(B, SC), dim3(BTH), 0, stream,
                     loc, conf, priors, targets, rank, idxa, facc, iacc, nposa);
  hipLaunchKernelGGL(mb_select, dim3(B), dim3(BTH), 0, stream, rank, nposa, facc, iacc);
  hipLaunchKernelGGL(mb_out,    dim3(1), dim3(64), 0, stream, facc, nposa, out, B);
}

// Round 4
// 259.986 us; speedup vs baseline: 1.2932x; 1.2932x over previous
//
#include <hip/hip_runtime.h>

#define PP 8732
#define NB 20
#define NC 21
#define BTH 256
#define NW 4
#define NCHUNK 35   // ceil(PP/BTH)

// ws layout (bytes):
//   0     : keys u64[B][NB]
//   20480 : facc float[8]   0=loss_l  1=conf loss (posce+negsum)
//   20512 : iacc int[8]     0=npos total
//   32768 : rankneg float[B][PP]   (lse - conf0, for every prior)
//   +B*PP*4 : meta uchar[B][PP]    (bestn<<1 | pos_by_threshold)
#define OFF_FACC 20480
#define OFF_IACC 20512
#define OFF_RANK 32768

__device__ __forceinline__ float sl1(float d){
  float a = fabsf(d);
  return a < 1.0f ? 0.5f*a*a : a - 0.5f;
}

// ---- 1: fused match + logsumexp. grid (B, NCHUNK) ----
// Wave-private conf staging: no block barrier between stage and compute.
extern "C" __global__ void __launch_bounds__(BTH)
mb_main(const float* __restrict__ conf_data,
        const float* __restrict__ priors,
        const float* __restrict__ targets,
        float* __restrict__ rankneg,
        unsigned char* __restrict__ meta,
        unsigned long long* __restrict__ keys)
{
  const int b = blockIdx.x, tid = threadIdx.x, lane = tid & 63, wid = tid >> 6;
  const int q0 = blockIdx.y*BTH + wid*64;                 // this wave's chunk
  const int cnt = (q0 < PP) ? ((PP - q0 < 64) ? (PP - q0) : 64) : 0;

  __shared__ float s_buf[NW][64*NC];                      // 21504 B, wave-private
  __shared__ float s_tr[NB][4];
  __shared__ unsigned long long s_keys[NW][NB];

  if (tid < NB*4){
    int n = tid>>2, k2 = tid&3;
    s_tr[n][k2] = targets[((long)b*NB + n)*5 + k2];
  }
  __syncthreads();

  unsigned long long bk[NB];
  #pragma unroll
  for (int n=0;n<NB;n++) bk[n]=0ULL;

  if (cnt > 0){
    // coalesced stage: 21 wave-instrs, 84 lines per 64 priors (minimum traffic)
    const float* cb = conf_data + ((long)b*PP + q0)*NC;
    float* sb = s_buf[wid];
    const int tot = cnt*NC;
    for (int j = lane; j < tot; j += 64) sb[j] = cb[j];
  }
  if (lane < cnt){
    const int p = q0 + lane;
    const float* v = &s_buf[wid][lane*NC];   // stride 21: 2-way bank alias (free)
    float m = v[0];
    #pragma unroll
    for (int c=1;c<NC;c++) m = fmaxf(m, v[c]);
    float s = 0.f;
    #pragma unroll
    for (int c=0;c<NC;c++) s += expf(v[c]-m);
    float lse = logf(s) + m;
    rankneg[(long)b*PP + p] = lse - v[0];

    float4 pr = reinterpret_cast<const float4*>(priors)[p];
    float bx1 = pr.x - pr.z*0.5f, by1 = pr.y - pr.w*0.5f;
    float bx2 = pr.x + pr.z*0.5f, by2 = pr.y + pr.w*0.5f;
    float area_b = (bx2-bx1)*(by2-by1);
    float bestov = -1.0f; int bestn = 0;
    #pragma unroll
    for (int n=0;n<NB;n++){
      float tx1=s_tr[n][0], ty1=s_tr[n][1], tx2=s_tr[n][2], ty2=s_tr[n][3];
      float lx=fmaxf(tx1,bx1), ly=fmaxf(ty1,by1);
      float rx=fminf(tx2,bx2), ry=fminf(ty2,by2);
      float w=fmaxf(rx-lx,0.f), h=fmaxf(ry-ly,0.f);
      float inter=w*h;
      float area_a=(tx2-tx1)*(ty2-ty1);
      float iou = inter/(area_a+area_b-inter);
      if (iou > bestov){ bestov=iou; bestn=n; }           // strict > = first-max
      bk[n] = ((unsigned long long)__float_as_uint(iou)<<32)
            | (unsigned long long)(0xFFFFFFFFu - (unsigned)p);  // tie -> min p
    }
    meta[(long)b*PP + p] = (unsigned char)((bestn<<1) | (bestov >= 0.5f ? 1 : 0));
  }

  // per-truth best-prior: wave reduce -> block merge -> 20 atomics/block
  #pragma unroll
  for (int n=0;n<NB;n++){
    unsigned long long k2 = bk[n];
    #pragma unroll
    for (int o=32;o;o>>=1){ unsigned long long w=__shfl_down(k2,o,64); if (w>k2) k2=w; }
    if (lane==0) s_keys[wid][n] = k2;
  }
  __syncthreads();
  if (tid < NB){
    unsigned long long m = s_keys[0][tid];
    #pragma unroll
    for (int w=1;w<NW;w++) if (s_keys[w][tid] > m) m = s_keys[w][tid];
    if (m) atomicMax(&keys[b*NB + tid], m);
  }
}

// ---- 2: fused scatter + positive losses + exact top-k. grid (B) ----
extern "C" __global__ void __launch_bounds__(BTH)
mb_select(const float* __restrict__ loc_data,
          const float* __restrict__ conf_data,
          const float* __restrict__ priors,
          const float* __restrict__ targets,
          const float* __restrict__ rankneg,
          const unsigned char* __restrict__ meta,
          const unsigned long long* __restrict__ keys,
          float* __restrict__ facc, int* __restrict__ iacc)
{
  const int b = blockIdx.x, tid = threadIdx.x, lane = tid & 63, wid = tid >> 6;
  __shared__ float s_val[PP];            // 34928 B
  __shared__ unsigned int s_meta4[PP/4]; // 8732 B
  __shared__ float s_tr[NB][4];
  __shared__ float s_lab[NB];
  __shared__ int   s_cnt[8];             // double-buffered search partials
  __shared__ float s_ff[2*NW];
  __shared__ int   s_ii[NW];
  __shared__ float s_delta;
  __shared__ int   s_spec, s_npos;
  unsigned char* s_meta = (unsigned char*)s_meta4;

  // stage rank + meta rows (coalesced vector loads; b*PP % 4 == 0)
  const float4* rr = reinterpret_cast<const float4*>(rankneg + (long)b*PP);
  float4* sv4 = reinterpret_cast<float4*>(s_val);
  for (int i=tid;i<PP/4;i+=BTH) sv4[i]=rr[i];
  const unsigned int* mr = reinterpret_cast<const unsigned int*>(meta + (long)b*PP);
  for (int i=tid;i<PP/4;i+=BTH) s_meta4[i]=mr[i];
  if (tid < NB*5){
    int n = tid/5, k2 = tid-n*5;
    float v = targets[((long)b*NB+n)*5+k2];
    if (k2<4) s_tr[n][k2]=v; else s_lab[n]=v;
  }
  if (tid==0){ s_spec=0; s_delta=0.f; }
  __syncthreads();

  // apply per-truth overrides in LDS, ascending n (max n wins), forced pos
  if (tid==0){
    for (int n=0;n<NB;n++){
      unsigned long long kk = keys[b*NB+n];
      int p = (int)(0xFFFFFFFFu - (unsigned)(kk & 0xFFFFFFFFULL));
      s_meta[p] = (unsigned char)((n<<1)|1);
    }
  }
  __syncthreads();

  // positive pass: losses + zero ranks; special-case flat index 0
  float ll=0.f, pc=0.f; int np=0;
  for (int p=tid;p<PP;p+=BTH){
    int mt = s_meta[p];
    if (mt & 1){
      np++;
      int n = mt>>1;
      int ct = (int)s_lab[n] + 1;
      const float* cp = conf_data + ((long)b*PP+p)*NC;
      float v0 = cp[0], vct = cp[ct];
      float rn = s_val[p];
      pc += rn + v0 - vct;                 // lse - v[ct]
      float4 pr = reinterpret_cast<const float4*>(priors)[p];
      float4 ld = reinterpret_cast<const float4*>(loc_data)[(long)b*PP+p];
      float tx1=s_tr[n][0],ty1=s_tr[n][1],tx2=s_tr[n][2],ty2=s_tr[n][3];
      float g0 = ((tx1+tx2)*0.5f - pr.x)/(0.1f*pr.z);
      float g1 = ((ty1+ty2)*0.5f - pr.y)/(0.1f*pr.w);
      float g2 = logf((tx2-tx1)/pr.z)/0.2f;
      float g3 = logf((ty2-ty1)/pr.w)/0.2f;
      ll += sl1(ld.x-g0)+sl1(ld.y-g1)+sl1(ld.z-g2)+sl1(ld.w-g3);
      s_val[p] = 0.f;                      // pos -> loss_c = 0 before ranking
    } else if (b==0 && p==0){
      // flat index 0: ranking value uses forced class 1; true ce uses class 0
      float v0 = conf_data[0], v1 = conf_data[1];
      float r0 = s_val[0];                 // lse - v0 = true ce
      float r0p = r0 + v0 - v1;            // lse - v1 = ranking value
      s_delta = r0 - r0p;
      s_spec = 1;
      s_val[0] = r0p;
    }
  }
  #pragma unroll
  for (int o=32;o;o>>=1){
    ll += __shfl_down(ll,o,64);
    pc += __shfl_down(pc,o,64);
    np += __shfl_down(np,o,64);
  }
  if (lane==0){ s_ff[wid]=ll; s_ff[NW+wid]=pc; s_ii[wid]=np; }
  __syncthreads();
  if (tid==0){
    float a=0.f,c2=0.f; int ni=0;
    for (int w=0;w<NW;w++){ a+=s_ff[w]; c2+=s_ff[NW+w]; ni+=s_ii[w]; }
    s_npos = ni;
    if (a  != 0.f) atomicAdd(&facc[0], a);
    if (c2 != 0.f) atomicAdd(&facc[1], c2);
    if (ni) atomicAdd(&iacc[0], ni);
  }
  __syncthreads();
  int k = s_npos*3; if (k > PP-1) k = PP-1;
  if (k > 0){
    // k-th largest via binary search on float bits (all values >= 0)
    unsigned lo=0u, hi=0x7f800000u;
    int it=0;
    while (lo < hi){
      unsigned mid = lo + ((hi - lo + 1u) >> 1);
      int c=0;
      for (int i=tid;i<PP/4;i+=BTH){
        float4 x = sv4[i];
        c += (__float_as_uint(x.x)>=mid) + (__float_as_uint(x.y)>=mid)
           + (__float_as_uint(x.z)>=mid) + (__float_as_uint(x.w)>=mid);
      }
      #pragma unroll
      for (int o=32;o;o>>=1) c += __shfl_down(c,o,64);
      int sl=(it&1)*4;
      if (lane==0) s_cnt[sl+wid]=c;
      __syncthreads();                    // single barrier per iter (dbuf slots)
      int tot = s_cnt[sl]+s_cnt[sl+1]+s_cnt[sl+2]+s_cnt[sl+3];
      if (tot >= k) lo = mid; else hi = mid - 1u;
      it++;
    }
    const unsigned vstar = lo;

    int cg=0; float sg=0.f;
    for (int i=tid;i<PP/4;i+=BTH){
      float4 x = sv4[i];
      if (__float_as_uint(x.x)>vstar){cg++;sg+=x.x;}
      if (__float_as_uint(x.y)>vstar){cg++;sg+=x.y;}
      if (__float_as_uint(x.z)>vstar){cg++;sg+=x.z;}
      if (__float_as_uint(x.w)>vstar){cg++;sg+=x.w;}
    }
    #pragma unroll
    for (int o=32;o;o>>=1){ cg += __shfl_down(cg,o,64); sg += __shfl_down(sg,o,64); }
    __syncthreads();
    if (lane==0){ s_ii[wid]=cg; s_ff[wid]=sg; }
    __syncthreads();
    if (tid==0){
      int cG=0; float sumG=0.f;
      for (int w=0;w<NW;w++){ cG+=s_ii[w]; sumG+=s_ff[w]; }
      int tie = k - cG;                    // >=1; stable ties take lowest indices
      float negsum = sumG + (float)tie * __uint_as_float(vstar);
      // index 0 is first among equal ties -> selected iff bits >= vstar
      if (b==0 && s_spec && __float_as_uint(s_val[0]) >= vstar) negsum += s_delta;
      atomicAdd(&facc[1], negsum);
    }
  }
}

// ---- 3: final ----
extern "C" __global__ void mb_out(const float* __restrict__ facc,
                                  const int* __restrict__ iacc,
                                  float* __restrict__ out)
{
  if (threadIdx.x==0 && blockIdx.x==0){
    float Nf = (float)iacc[0];
    out[0] = facc[0] / Nf;
    out[1] = facc[1] / Nf;
  }
}

extern "C" void kernel_launch(void* const* d_in, const int* in_sizes, int n_in,
                              void* d_out, int out_size, void* d_ws, size_t ws_size,
                              hipStream_t stream) {
  const float* loc     = (const float*)d_in[0];
  const float* conf    = (const float*)d_in[1];
  const float* priors  = (const float*)d_in[2];
  const float* targets = (const float*)d_in[3];
  float* out = (float*)d_out;
  int B = in_sizes[0] / (PP*4);

  char* ws = (char*)d_ws;
  unsigned long long* keys = (unsigned long long*)ws;
  float* facc = (float*)(ws + OFF_FACC);
  int*   iacc = (int*)(ws + OFF_IACC);
  float* rankneg = (float*)(ws + OFF_RANK);
  unsigned char* metaa = (unsigned char*)(ws + OFF_RANK + (size_t)B*PP*4);

  hipMemsetAsync(d_ws, 0, 32768, stream);
  hipLaunchKernelGGL(mb_main,   dim3(B, NCHUNK), dim3(BTH), 0, stream,
                     conf, priors, targets, rankneg, metaa, keys);
  hipLaunchKernelGGL(mb_select, dim3(B), dim3(BTH), 0, stream,
                     loc, conf, priors, targets, rankneg, metaa, keys, facc, iacc);
  hipLaunchKernelGGL(mb_out,    dim3(1), dim3(64), 0, stream, facc, iacc, out);
}

// Round 5
// 218.948 us; speedup vs baseline: 1.5355x; 1.1874x over previous
//
#include <hip/hip_runtime.h>

#define PP 8732
#define NB 20
#define NC 21
#define BTH 256
#define NCH 35          // ceil(PP/256)
#define BTS 1024
#define NWS (BTS/64)

// ws layout (runtime offsets computed in kernel_launch):
//   0    : ticket int (memset to 0 each call)
//   64   : rowres float[B][4]  (ll, conf_loss, npos, pad)
//   4096 : keys2 u64[B][NCH][NB]   plain stores, no atomics
//   then : rankneg float[B][PP]
//   then : meta uchar[B][PP]  (bestn<<1 | pos_by_threshold)

__device__ __forceinline__ float sl1(float d){
  float a = fabsf(d);
  return a < 1.0f ? 0.5f*a*a : a - 0.5f;
}

// ---- 1: fused match + logsumexp. grid (B, NCH) ----
extern "C" __global__ void __launch_bounds__(BTH)
mb_main(const float* __restrict__ conf_data,
        const float* __restrict__ priors,
        const float* __restrict__ targets,
        float* __restrict__ rankneg,
        unsigned char* __restrict__ meta,
        unsigned long long* __restrict__ keys2)
{
  const int b = blockIdx.x, chunk = blockIdx.y;
  const int tid = threadIdx.x, lane = tid & 63, wid = tid >> 6;
  const int q0 = chunk*BTH + wid*64;
  const int cnt = (q0 < PP) ? ((PP - q0 < 64) ? (PP - q0) : 64) : 0;

  __shared__ float s_buf[4][64*NC];          // 21504 B, wave-private
  __shared__ float4 s_tr4[NB];
  __shared__ unsigned long long s_keys[4][NB];

  if (tid < NB*4){
    int n = tid>>2, k2 = tid&3;
    ((float*)s_tr4)[tid] = targets[((long)b*NB + n)*5 + k2];
  }
  __syncthreads();

  // wave-private float4 staging (cb 16B-aligned: q0 mult of 64, PP*NC*b mult of 4)
  if (cnt == 64){
    const float4* cb4 = reinterpret_cast<const float4*>(conf_data + ((long)b*PP + q0)*NC);
    float4* sb4 = reinterpret_cast<float4*>(s_buf[wid]);
    #pragma unroll
    for (int ii=0; ii<6; ii++){
      int i = ii*64 + lane;
      if (i < 336) sb4[i] = cb4[i];          // 336 = 64*21/4
    }
  } else if (cnt > 0){
    const float4* cb4 = reinterpret_cast<const float4*>(conf_data + ((long)b*PP + q0)*NC);
    float4* sb4 = reinterpret_cast<float4*>(s_buf[wid]);
    const int tot4 = (cnt*NC) >> 2;          // cnt=28 -> 147 (28*21 mult of 4)
    for (int i=lane; i<tot4; i+=64) sb4[i] = cb4[i];
  }

  const bool valid = (lane < cnt);
  const int p  = q0 + lane;
  const int pl = valid ? p : 0;

  // logsumexp from LDS (stride-21 reads: 2-way bank alias = free)
  const float* v = s_buf[wid] + lane*NC;
  float m = v[0];
  #pragma unroll
  for (int c=1;c<NC;c++) m = fmaxf(m, v[c]);
  float s = 0.f;
  #pragma unroll
  for (int c=0;c<NC;c++) s += __expf(v[c]-m);
  float lse = __logf(s) + m;
  if (valid) rankneg[(long)b*PP + p] = lse - v[0];

  float4 pr = reinterpret_cast<const float4*>(priors)[pl];
  float bx1 = pr.x - pr.z*0.5f, by1 = pr.y - pr.w*0.5f;
  float bx2 = pr.x + pr.z*0.5f, by2 = pr.y + pr.w*0.5f;
  float area_b = (bx2-bx1)*(by2-by1);
  float bestov = -1.0f; int bestn = 0;

  #pragma unroll
  for (int n=0;n<NB;n++){
    float4 t = s_tr4[n];                     // one ds_read_b128, broadcast
    float lx=fmaxf(t.x,bx1), ly=fmaxf(t.y,by1);
    float rx=fminf(t.z,bx2), ry=fminf(t.w,by2);
    float iw=fmaxf(rx-lx,0.f), ih=fmaxf(ry-ly,0.f);
    float inter = iw*ih;
    float aa = (t.z-t.x)*(t.w-t.y);
    float uni = aa + area_b - inter;
    float iou = inter * __builtin_amdgcn_rcpf(uni);
    if (iou > bestov){ bestov=iou; bestn=n; }          // strict > = first-max over n

    // wave argmax over p: f32 max butterfly + ballot (tie -> lowest lane = min p)
    float wm = valid ? iou : -1.0f;
    #pragma unroll
    for (int o=32;o;o>>=1) wm = fmaxf(wm, __shfl_xor(wm, o, 64));
    unsigned long long mk = __ballot(valid && (iou == wm));
    if (mk){
      if (lane == __ffsll((long long)mk)-1)
        s_keys[wid][n] = ((unsigned long long)__float_as_uint(iou)<<32)
                       | (unsigned long long)(0xFFFFFFFFu - (unsigned)p);
    } else if (lane==0){
      s_keys[wid][n] = 0ULL;
    }
  }

  if (valid) meta[(long)b*PP + p] = (unsigned char)((bestn<<1) | (bestov >= 0.5f ? 1 : 0));

  __syncthreads();
  if (tid < NB){
    unsigned long long mx = s_keys[0][tid];
    #pragma unroll
    for (int w=1;w<4;w++) if (s_keys[w][tid] > mx) mx = s_keys[w][tid];
    keys2[((long)b*NCH + chunk)*NB + tid] = mx;        // plain store
  }
}

// ---- 2: fused scatter + positive losses + top-k + final reduce. grid (B) ----
extern "C" __global__ void __launch_bounds__(BTS)
mb_select(const float* __restrict__ loc_data,
          const float* __restrict__ conf_data,
          const float* __restrict__ priors,
          const float* __restrict__ targets,
          const float* __restrict__ rankneg,
          const unsigned char* __restrict__ meta,
          const unsigned long long* __restrict__ keys2,
          float* __restrict__ rowres, int* __restrict__ ticket,
          float* __restrict__ out, int Bn)
{
  const int b = blockIdx.x, tid = threadIdx.x, lane = tid & 63, wid = tid >> 6;
  __shared__ float s_val[PP];              // 34928
  __shared__ unsigned int s_meta4[PP/4];   // 8732
  __shared__ float4 s_tr4[NB];
  __shared__ float s_lab[NB];
  __shared__ int   s_bp[NB];
  __shared__ int   s_cnt[2][NWS];
  __shared__ float s_fa[NWS], s_fb[NWS], s_fc[NWS];
  __shared__ int   s_ia[NWS];
  __shared__ float s_rowll, s_rowpc, s_delta;
  __shared__ int   s_npos, s_spec, s_last;
  unsigned char* s_meta = (unsigned char*)s_meta4;
  float4* sv4 = reinterpret_cast<float4*>(s_val);

  // stage rank + meta rows
  const float4* rr = reinterpret_cast<const float4*>(rankneg + (long)b*PP);
  for (int i=tid;i<PP/4;i+=BTS) sv4[i]=rr[i];
  const unsigned int* mr = reinterpret_cast<const unsigned int*>(meta + (long)b*PP);
  for (int i=tid;i<PP/4;i+=BTS) s_meta4[i]=mr[i];
  if (tid < NB*5){
    int n = tid/5, k2 = tid-n*5;
    float vv = targets[((long)b*NB+n)*5+k2];
    if (k2<4) ((float*)&s_tr4[n])[k2]=vv; else s_lab[n]=vv;
  }
  if (tid < NB){
    unsigned long long mx = 0ULL;
    #pragma unroll
    for (int c=0;c<NCH;c++){
      unsigned long long kk = keys2[((long)b*NCH + c)*NB + tid];
      if (kk > mx) mx = kk;
    }
    s_bp[tid] = (int)(0xFFFFFFFFu - (unsigned)(mx & 0xFFFFFFFFULL));
  }
  if (tid==0){ s_spec=0; s_delta=0.f; }
  __syncthreads();

  // overrides in LDS, ascending n (max n wins on collision), forced positive
  if (tid==0){
    for (int n=0;n<NB;n++) s_meta[s_bp[n]] = (unsigned char)((n<<1)|1);
  }
  __syncthreads();

  // positive pass
  float ll=0.f, pc=0.f; int np=0;
  for (int p=tid;p<PP;p+=BTS){
    int mt = s_meta[p];
    if (mt & 1){
      np++;
      int n = mt>>1;
      int ct = (int)s_lab[n] + 1;
      const float* cp = conf_data + ((long)b*PP+p)*NC;
      float v0 = cp[0], vct = cp[ct];
      pc += s_val[p] + v0 - vct;             // lse - v[ct]
      float4 t = s_tr4[n];
      float4 pr = reinterpret_cast<const float4*>(priors)[p];
      float4 ld = reinterpret_cast<const float4*>(loc_data)[(long)b*PP+p];
      float g0 = ((t.x+t.z)*0.5f - pr.x)/(0.1f*pr.z);
      float g1 = ((t.y+t.w)*0.5f - pr.y)/(0.1f*pr.w);
      float g2 = __logf((t.z-t.x)/pr.z)/0.2f;
      float g3 = __logf((t.w-t.y)/pr.w)/0.2f;
      ll += sl1(ld.x-g0)+sl1(ld.y-g1)+sl1(ld.z-g2)+sl1(ld.w-g3);
      s_val[p] = 0.f;                        // pos -> loss_c = 0
    } else if (b==0 && p==0){
      // flat index 0: ranking value uses forced class 1; true ce uses class 0
      float v0 = conf_data[0], v1 = conf_data[1];
      float r0 = s_val[0];
      float r0p = r0 + v0 - v1;
      s_delta = r0 - r0p;
      s_spec = 1;
      s_val[0] = r0p;
    }
  }
  #pragma unroll
  for (int o=32;o;o>>=1){
    ll += __shfl_down(ll,o,64);
    pc += __shfl_down(pc,o,64);
    np += __shfl_down(np,o,64);
  }
  if (lane==0){ s_fa[wid]=ll; s_fb[wid]=pc; s_ia[wid]=np; }
  __syncthreads();
  if (tid==0){
    float a=0.f,c2=0.f; int ni=0;
    for (int w=0;w<NWS;w++){ a+=s_fa[w]; c2+=s_fb[w]; ni+=s_ia[w]; }
    s_rowll=a; s_rowpc=c2; s_npos=ni;
  }
  __syncthreads();
  const int num_pos = s_npos;
  int k = num_pos*3; if (k > PP-1) k = PP-1;

  float negsum = 0.f;
  if (k > 0){
    // k-th largest via binary search on float bits (all values >= 0)
    unsigned lo=0u, hi=0x7f800000u;
    int it=0;
    while (lo < hi){
      unsigned mid = lo + ((hi - lo + 1u) >> 1);
      int c=0;
      for (int i=tid;i<PP/4;i+=BTS){
        float4 x = sv4[i];
        c += (__float_as_uint(x.x)>=mid) + (__float_as_uint(x.y)>=mid)
           + (__float_as_uint(x.z)>=mid) + (__float_as_uint(x.w)>=mid);
      }
      #pragma unroll
      for (int o=32;o;o>>=1) c += __shfl_down(c,o,64);
      int sl2 = it&1;
      if (lane==0) s_cnt[sl2][wid]=c;
      __syncthreads();
      int tot=0;
      #pragma unroll
      for (int w=0;w<NWS;w++) tot += s_cnt[sl2][w];
      if (tot >= k) lo = mid; else hi = mid - 1u;
      it++;
    }
    const unsigned vstar = lo;

    int cg=0; float sg=0.f;
    for (int i=tid;i<PP/4;i+=BTS){
      float4 x = sv4[i];
      if (__float_as_uint(x.x)>vstar){cg++;sg+=x.x;}
      if (__float_as_uint(x.y)>vstar){cg++;sg+=x.y;}
      if (__float_as_uint(x.z)>vstar){cg++;sg+=x.z;}
      if (__float_as_uint(x.w)>vstar){cg++;sg+=x.w;}
    }
    #pragma unroll
    for (int o=32;o;o>>=1){ cg += __shfl_down(cg,o,64); sg += __shfl_down(sg,o,64); }
    __syncthreads();
    if (lane==0){ s_ia[wid]=cg; s_fa[wid]=sg; }
    __syncthreads();
    if (tid==0){
      int cG=0; float sumG=0.f;
      for (int w=0;w<NWS;w++){ cG+=s_ia[w]; sumG+=s_fa[w]; }
      int tie = k - cG;                      // >=1; stable ties take lowest indices
      negsum = sumG + (float)tie * __uint_as_float(vstar);
      // index 0 is lowest index -> first among equal ties; selected iff bits >= vstar
      if (b==0 && s_spec && __float_as_uint(s_val[0]) >= vstar) negsum += s_delta;
    }
  }

  // row results + ticket
  if (tid==0){
    rowres[b*4+0] = s_rowll;
    rowres[b*4+1] = s_rowpc + negsum;
    rowres[b*4+2] = (float)num_pos;
    __threadfence();
    int t = atomicAdd(ticket, 1);
    s_last = (t == gridDim.x - 1) ? 1 : 0;
  }
  __syncthreads();

  if (s_last){
    __threadfence();
    float a0=0.f, a1=0.f, a2=0.f;
    for (int i=tid;i<Bn;i+=BTS){
      a0 += rowres[i*4+0]; a1 += rowres[i*4+1]; a2 += rowres[i*4+2];
    }
    #pragma unroll
    for (int o=32;o;o>>=1){
      a0 += __shfl_down(a0,o,64);
      a1 += __shfl_down(a1,o,64);
      a2 += __shfl_down(a2,o,64);
    }
    if (lane==0){ s_fa[wid]=a0; s_fb[wid]=a1; s_fc[wid]=a2; }
    __syncthreads();
    if (tid==0){
      float A0=0.f,A1=0.f,A2=0.f;
      for (int w=0;w<NWS;w++){ A0+=s_fa[w]; A1+=s_fb[w]; A2+=s_fc[w]; }
      out[0] = A0/A2;
      out[1] = A1/A2;
    }
  }
}

extern "C" void kernel_launch(void* const* d_in, const int* in_sizes, int n_in,
                              void* d_out, int out_size, void* d_ws, size_t ws_size,
                              hipStream_t stream) {
  const float* loc     = (const float*)d_in[0];
  const float* conf    = (const float*)d_in[1];
  const float* priors  = (const float*)d_in[2];
  const float* targets = (const float*)d_in[3];
  float* out = (float*)d_out;
  int B = in_sizes[0] / (PP*4);

  char* ws = (char*)d_ws;
  int*   ticket = (int*)ws;
  float* rowres = (float*)(ws + 64);
  unsigned long long* keys2 = (unsigned long long*)(ws + 4096);
  size_t off_rank = 4096 + (size_t)B*NCH*NB*8;
  float* rankneg = (float*)(ws + off_rank);
  unsigned char* metaa = (unsigned char*)(ws + off_rank + (size_t)B*PP*4);

  hipMemsetAsync(d_ws, 0, 64, stream);
  hipLaunchKernelGGL(mb_main,   dim3(B, NCH), dim3(BTH), 0, stream,
                     conf, priors, targets, rankneg, metaa, keys2);
  hipLaunchKernelGGL(mb_select, dim3(B), dim3(BTS), 0, stream,
                     loc, conf, priors, targets, rankneg, metaa, keys2,
                     rowres, ticket, out, B);
}

// Round 6
// 214.179 us; speedup vs baseline: 1.5697x; 1.0223x over previous
//
#include <hip/hip_runtime.h>

#define PP 8732
#define NB 20
#define NC 21
#define BTH 256
#define NCH 35          // ceil(PP/256)
#define BTS 1024
#define NWS (BTS/64)

__device__ __forceinline__ float sl1(float d){
  float a = fabsf(d);
  return a < 1.0f ? 0.5f*a*a : a - 0.5f;
}

// Full 64-lane max via DPP (VALU pipe only); result valid in lane 63, broadcast
// to all lanes through readlane. bound_ctrl=1 injects 0.0 at row edges -- harmless
// here since the true max is always >= 0 (IoU >= 0 and lane 0 is always valid).
__device__ __forceinline__ float wave_max64(float x){
  int t;
  t = __builtin_amdgcn_update_dpp(0, __float_as_int(x), 0x111, 0xF, 0xF, true); x = fmaxf(x, __int_as_float(t));
  t = __builtin_amdgcn_update_dpp(0, __float_as_int(x), 0x112, 0xF, 0xF, true); x = fmaxf(x, __int_as_float(t));
  t = __builtin_amdgcn_update_dpp(0, __float_as_int(x), 0x114, 0xF, 0xF, true); x = fmaxf(x, __int_as_float(t));
  t = __builtin_amdgcn_update_dpp(0, __float_as_int(x), 0x118, 0xF, 0xF, true); x = fmaxf(x, __int_as_float(t));
  t = __builtin_amdgcn_update_dpp(0, __float_as_int(x), 0x142, 0xF, 0xF, true); x = fmaxf(x, __int_as_float(t));
  t = __builtin_amdgcn_update_dpp(0, __float_as_int(x), 0x143, 0xF, 0xF, true); x = fmaxf(x, __int_as_float(t));
  return __int_as_float(__builtin_amdgcn_readlane(__float_as_int(x), 63));
}

// ---- 1: fused match + logsumexp. grid (B, NCH) ----
extern "C" __global__ void __launch_bounds__(BTH)
mb_main(const float* __restrict__ conf_data,
        const float* __restrict__ priors,
        const float* __restrict__ targets,
        float* __restrict__ rankneg,
        unsigned char* __restrict__ meta,
        unsigned long long* __restrict__ keys2)
{
  const int b = blockIdx.x, chunk = blockIdx.y;
  const int tid = threadIdx.x, lane = tid & 63, wid = tid >> 6;
  const int q0 = chunk*BTH + wid*64;
  const int cnt = (q0 < PP) ? ((PP - q0 < 64) ? (PP - q0) : 64) : 0;

  __shared__ float s_buf[4][64*NC];          // 21504 B, wave-private
  __shared__ float4 s_tr4[NB];
  __shared__ unsigned long long s_keys[4][NB];

  if (tid < NB*4){
    int n = tid>>2, k2 = tid&3;
    ((float*)s_tr4)[tid] = targets[((long)b*NB + n)*5 + k2];
  }
  if (lane < NB) s_keys[wid][lane] = 0ULL;   // same-wave init (cnt==0 waves)
  __syncthreads();

  // wave-private float4 staging
  if (cnt == 64){
    const float4* cb4 = reinterpret_cast<const float4*>(conf_data + ((long)b*PP + q0)*NC);
    float4* sb4 = reinterpret_cast<float4*>(s_buf[wid]);
    #pragma unroll
    for (int ii=0; ii<6; ii++){
      int i = ii*64 + lane;
      if (i < 336) sb4[i] = cb4[i];          // 336 = 64*21/4
    }
  } else if (cnt > 0){
    const float4* cb4 = reinterpret_cast<const float4*>(conf_data + ((long)b*PP + q0)*NC);
    float4* sb4 = reinterpret_cast<float4*>(s_buf[wid]);
    const int tot4 = (cnt*NC) >> 2;
    for (int i=lane; i<tot4; i+=64) sb4[i] = cb4[i];
  }

  const bool valid = (lane < cnt);
  const int p  = q0 + lane;
  const int pl = valid ? p : 0;

  // logsumexp from LDS (stride-21: 2-way bank alias = free)
  const float* v = s_buf[wid] + lane*NC;
  float m = v[0];
  #pragma unroll
  for (int c=1;c<NC;c++) m = fmaxf(m, v[c]);
  float s = 0.f;
  #pragma unroll
  for (int c=0;c<NC;c++) s += __expf(v[c]-m);
  float lse = __logf(s) + m;
  if (valid) rankneg[(long)b*PP + p] = lse - v[0];

  float4 pr = reinterpret_cast<const float4*>(priors)[pl];
  float bx1 = pr.x - pr.z*0.5f, by1 = pr.y - pr.w*0.5f;
  float bx2 = pr.x + pr.z*0.5f, by2 = pr.y + pr.w*0.5f;
  float area_b = (bx2-bx1)*(by2-by1);
  float bestov = -1.0f; int bestn = 0;

  for (int n=0;n<NB;n++){
    float4 t = s_tr4[n];                     // ds_read_b128 broadcast
    float lx=fmaxf(t.x,bx1), ly=fmaxf(t.y,by1);
    float rx=fminf(t.z,bx2), ry=fminf(t.w,by2);
    float iw=fmaxf(rx-lx,0.f), ih=fmaxf(ry-ly,0.f);
    float inter = iw*ih;
    float aa = (t.z-t.x)*(t.w-t.y);
    float iou = inter * __builtin_amdgcn_rcpf(aa + area_b - inter);
    if (iou > bestov){ bestov=iou; bestn=n; }          // strict > = first-max over n

    // per-truth wave argmax: DPP max (VALU) + ballot; tie -> lowest lane = min p
    float iouv = valid ? iou : -1.0f;
    float wmax = wave_max64(iouv);
    unsigned long long mk = __ballot(valid && (iou == wmax));
    if (mk){
      int wlane = __ffsll((long long)mk) - 1;
      if (lane == wlane)
        s_keys[wid][n] = ((unsigned long long)__float_as_uint(iou)<<32)
                       | (unsigned long long)(0xFFFFFFFFu - (unsigned)p);
    }
  }

  if (valid) meta[(long)b*PP + p] = (unsigned char)((bestn<<1) | (bestov >= 0.5f ? 1 : 0));

  __syncthreads();
  if (tid < NB){
    unsigned long long mx = s_keys[0][tid];
    #pragma unroll
    for (int w=1;w<4;w++) if (s_keys[w][tid] > mx) mx = s_keys[w][tid];
    keys2[((long)b*NCH + chunk)*NB + tid] = mx;        // plain store
  }
}

// ---- 2: fused scatter + positive losses + top-k + final reduce. grid (B) ----
extern "C" __global__ void __launch_bounds__(BTS)
mb_select(const float* __restrict__ loc_data,
          const float* __restrict__ conf_data,
          const float* __restrict__ priors,
          const float* __restrict__ targets,
          const float* __restrict__ rankneg,
          const unsigned char* __restrict__ meta,
          const unsigned long long* __restrict__ keys2,
          float* __restrict__ rowres, int* __restrict__ ticket,
          float* __restrict__ out, int Bn)
{
  const int b = blockIdx.x, tid = threadIdx.x, lane = tid & 63, wid = tid >> 6;
  __shared__ float s_val[PP];              // 34928
  __shared__ unsigned int s_meta4[PP/4];   // 8732
  __shared__ float4 s_tr4[NB];
  __shared__ float s_lab[NB];
  __shared__ int   s_bp[NB];
  __shared__ int   s_cnt[2][NWS];
  __shared__ float s_fa[NWS], s_fb[NWS], s_fc[NWS];
  __shared__ int   s_ia[NWS];
  __shared__ float s_rowll, s_rowpc, s_delta;
  __shared__ int   s_npos, s_spec, s_last;
  unsigned char* s_meta = (unsigned char*)s_meta4;
  float4* sv4 = reinterpret_cast<float4*>(s_val);

  const float4* rr = reinterpret_cast<const float4*>(rankneg + (long)b*PP);
  for (int i=tid;i<PP/4;i+=BTS) sv4[i]=rr[i];
  const unsigned int* mr = reinterpret_cast<const unsigned int*>(meta + (long)b*PP);
  for (int i=tid;i<PP/4;i+=BTS) s_meta4[i]=mr[i];
  if (tid < NB*5){
    int n = tid/5, k2 = tid-n*5;
    float vv = targets[((long)b*NB+n)*5+k2];
    if (k2<4) ((float*)&s_tr4[n])[k2]=vv; else s_lab[n]=vv;
  }
  if (tid < NB){
    unsigned long long mx = 0ULL;
    #pragma unroll
    for (int c=0;c<NCH;c++){
      unsigned long long kk = keys2[((long)b*NCH + c)*NB + tid];
      if (kk > mx) mx = kk;
    }
    s_bp[tid] = (int)(0xFFFFFFFFu - (unsigned)(mx & 0xFFFFFFFFULL));
  }
  if (tid==0){ s_spec=0; s_delta=0.f; }
  __syncthreads();

  // overrides, ascending n (max n wins on collisions), forced positive
  if (tid==0){
    for (int n=0;n<NB;n++) s_meta[s_bp[n]] = (unsigned char)((n<<1)|1);
  }
  __syncthreads();

  // positive pass
  float ll=0.f, pc=0.f; int np=0;
  for (int p=tid;p<PP;p+=BTS){
    int mt = s_meta[p];
    if (mt & 1){
      np++;
      int n = mt>>1;
      int ct = (int)s_lab[n] + 1;
      const float* cp = conf_data + ((long)b*PP+p)*NC;
      float v0 = cp[0], vct = cp[ct];
      pc += s_val[p] + v0 - vct;             // lse - v[ct]
      float4 t = s_tr4[n];
      float4 pr = reinterpret_cast<const float4*>(priors)[p];
      float4 ld = reinterpret_cast<const float4*>(loc_data)[(long)b*PP+p];
      float g0 = ((t.x+t.z)*0.5f - pr.x)/(0.1f*pr.z);
      float g1 = ((t.y+t.w)*0.5f - pr.y)/(0.1f*pr.w);
      float g2 = __logf((t.z-t.x)/pr.z)/0.2f;
      float g3 = __logf((t.w-t.y)/pr.w)/0.2f;
      ll += sl1(ld.x-g0)+sl1(ld.y-g1)+sl1(ld.z-g2)+sl1(ld.w-g3);
      s_val[p] = 0.f;
    } else if (b==0 && p==0){
      float v0 = conf_data[0], v1 = conf_data[1];
      float r0 = s_val[0];                   // lse - v0 = true ce
      float r0p = r0 + v0 - v1;              // lse - v1 = ranking value
      s_delta = r0 - r0p;
      s_spec = 1;
      s_val[0] = r0p;
    }
  }
  #pragma unroll
  for (int o=32;o;o>>=1){
    ll += __shfl_down(ll,o,64);
    pc += __shfl_down(pc,o,64);
    np += __shfl_down(np,o,64);
  }
  if (lane==0){ s_fa[wid]=ll; s_fb[wid]=pc; s_ia[wid]=np; }
  __syncthreads();

  // cache this thread's rank values in registers (zero-pad tail: exact-safe)
  float4 rv0 = sv4[tid];
  float4 rv1 = sv4[tid+1024];
  float4 rv2 = (tid < PP/4-2048) ? sv4[tid+2048]
                                 : make_float4(0.f,0.f,0.f,0.f);

  if (tid==0){
    float a=0.f,c2=0.f; int ni=0;
    for (int w=0;w<NWS;w++){ a+=s_fa[w]; c2+=s_fb[w]; ni+=s_ia[w]; }
    s_rowll=a; s_rowpc=c2; s_npos=ni;
  }
  __syncthreads();
  const int num_pos = s_npos;
  int k = num_pos*3; if (k > PP-1) k = PP-1;

  float negsum = 0.f;
  if (k > 0){
    // k-th largest via binary search on float bits; values cached in registers
    unsigned lo=0u, hi=0x7f800000u;
    int it=0;
    while (lo < hi){
      unsigned mid = lo + ((hi - lo + 1u) >> 1);
      int c = (__float_as_uint(rv0.x)>=mid) + (__float_as_uint(rv0.y)>=mid)
            + (__float_as_uint(rv0.z)>=mid) + (__float_as_uint(rv0.w)>=mid)
            + (__float_as_uint(rv1.x)>=mid) + (__float_as_uint(rv1.y)>=mid)
            + (__float_as_uint(rv1.z)>=mid) + (__float_as_uint(rv1.w)>=mid)
            + (__float_as_uint(rv2.x)>=mid) + (__float_as_uint(rv2.y)>=mid)
            + (__float_as_uint(rv2.z)>=mid) + (__float_as_uint(rv2.w)>=mid);
      #pragma unroll
      for (int o=32;o;o>>=1) c += __shfl_down(c,o,64);
      int sl2 = it&1;
      if (lane==0) s_cnt[sl2][wid]=c;
      __syncthreads();
      int tot=0;
      #pragma unroll
      for (int w=0;w<NWS;w++) tot += s_cnt[sl2][w];
      if (tot >= k) lo = mid; else hi = mid - 1u;
      it++;
    }
    const unsigned vstar = lo;

    int cg=0; float sg=0.f;
    #define ACC(x) if (__float_as_uint(x)>vstar){cg++;sg+=(x);}
    ACC(rv0.x) ACC(rv0.y) ACC(rv0.z) ACC(rv0.w)
    ACC(rv1.x) ACC(rv1.y) ACC(rv1.z) ACC(rv1.w)
    ACC(rv2.x) ACC(rv2.y) ACC(rv2.z) ACC(rv2.w)
    #undef ACC
    #pragma unroll
    for (int o=32;o;o>>=1){ cg += __shfl_down(cg,o,64); sg += __shfl_down(sg,o,64); }
    __syncthreads();
    if (lane==0){ s_ia[wid]=cg; s_fa[wid]=sg; }
    __syncthreads();
    if (tid==0){
      int cG=0; float sumG=0.f;
      for (int w=0;w<NWS;w++){ cG+=s_ia[w]; sumG+=s_fa[w]; }
      int tie = k - cG;                      // >=1; stable ties take lowest indices
      negsum = sumG + (float)tie * __uint_as_float(vstar);
      if (b==0 && s_spec && __float_as_uint(s_val[0]) >= vstar) negsum += s_delta;
    }
  }

  if (tid==0){
    rowres[b*4+0] = s_rowll;
    rowres[b*4+1] = s_rowpc + negsum;
    rowres[b*4+2] = (float)num_pos;
    __threadfence();
    int t = atomicAdd(ticket, 1);
    s_last = (t == gridDim.x - 1) ? 1 : 0;
  }
  __syncthreads();

  if (s_last){
    __threadfence();
    float a0=0.f, a1=0.f, a2=0.f;
    for (int i=tid;i<Bn;i+=BTS){
      a0 += rowres[i*4+0]; a1 += rowres[i*4+1]; a2 += rowres[i*4+2];
    }
    #pragma unroll
    for (int o=32;o;o>>=1){
      a0 += __shfl_down(a0,o,64);
      a1 += __shfl_down(a1,o,64);
      a2 += __shfl_down(a2,o,64);
    }
    if (lane==0){ s_fa[wid]=a0; s_fb[wid]=a1; s_fc[wid]=a2; }
    __syncthreads();
    if (tid==0){
      float A0=0.f,A1=0.f,A2=0.f;
      for (int w=0;w<NWS;w++){ A0+=s_fa[w]; A1+=s_fb[w]; A2+=s_fc[w]; }
      out[0] = A0/A2;
      out[1] = A1/A2;
    }
  }
}

extern "C" void kernel_launch(void* const* d_in, const int* in_sizes, int n_in,
                              void* d_out, int out_size, void* d_ws, size_t ws_size,
                              hipStream_t stream) {
  const float* loc     = (const float*)d_in[0];
  const float* conf    = (const float*)d_in[1];
  const float* priors  = (const float*)d_in[2];
  const float* targets = (const float*)d_in[3];
  float* out = (float*)d_out;
  int B = in_sizes[0] / (PP*4);

  char* ws = (char*)d_ws;
  int*   ticket = (int*)ws;
  float* rowres = (float*)(ws + 64);
  unsigned long long* keys2 = (unsigned long long*)(ws + 4096);
  size_t off_rank = 4096 + (size_t)B*NCH*NB*8;
  float* rankneg = (float*)(ws + off_rank);
  unsigned char* metaa = (unsigned char*)(ws + off_rank + (size_t)B*PP*4);

  hipMemsetAsync(d_ws, 0, 64, stream);
  hipLaunchKernelGGL(mb_main,   dim3(B, NCH), dim3(BTH), 0, stream,
                     conf, priors, targets, rankneg, metaa, keys2);
  hipLaunchKernelGGL(mb_select, dim3(B), dim3(BTS), 0, stream,
                     loc, conf, priors, targets, rankneg, metaa, keys2,
                     rowres, ticket, out, B);
}